// Round 3
// baseline (138.580 us; speedup 1.0000x reference)
//
#include <hip/hip_runtime.h>

#define B_SZ 256
#define RNODES 1152
#define KDIM 9216                 // 1152*8
#define COUT 16
#define NCAPS 10
#define WSTRIDE (KDIM*COUT)       // 147456 floats per capsule

#define LROW 40                   // 32 k + 8 pad (ushorts) -> 80B rows
#define WBUF (NCAPS*COUT*LROW)    // 6400 ushorts = 12.8 KB per step buffer
#define STEPS 3
#define SPLITS 96                 // 96 * 3 * 32 = 9216 = KDIM
#define NBLK (SPLITS*4)           // 384
#define PARTL 10240               // per-block partial: 10 caps * 64 rows * 16
#define FLAGS_OFF ((size_t)NBLK * PARTL)   // floats; flags live after partials
#define MAGIC 0x5A5A5A5Au

using bf16x8 = __attribute__((ext_vector_type(8))) short;
using f32x4  = __attribute__((ext_vector_type(4))) float;

__device__ __forceinline__ unsigned short f2bf(float f) {
  unsigned int u = __builtin_bit_cast(unsigned int, f);
  u += 0x7FFFu + ((u >> 16) & 1u);   // round-to-nearest-even
  return (unsigned short)(u >> 16);
}

// One fused kernel. grid = 384: block bid -> (ks = bid>>2, mt = bid&3).
// All blocks: GEMM split + partial store + release flag (magic; 0xAA poison is
// a guaranteed non-magic init, so no zeroing node needed).
// Blocks bid<160: additionally reduce 96 splits for 256 outputs + squash.
// Deadlock-free: spinners only wait on blocks that never wait.
__global__ __launch_bounds__(256) void caps_fused(const float* __restrict__ x,
                                                  const float* __restrict__ W,
                                                  float* __restrict__ ws,
                                                  float* __restrict__ out) {
  __shared__ unsigned short wbuf[STEPS][WBUF];   // 38.4 KB
  const int tid = threadIdx.x;
  const int bid = blockIdx.x;
  const int ks  = bid >> 2;
  const int mt  = bid & 3;
  const int b0  = mt * 64;
  const int k0  = ks * (STEPS * 32);

  const int lane = tid & 63;
  const int wv   = tid >> 6;        // wave -> 16-row sub-tile
  const int q    = lane >> 4;       // k-quad
  const int m16  = lane & 15;

  // ---- issue ALL W loads up front (15 float4/thread, one HBM round-trip) ----
  const int c4 = tid >> 5;          // + 8*j
  const int kl = tid & 31;
  float4 pw[STEPS][5];
#pragma unroll
  for (int s = 0; s < STEPS; ++s)
#pragma unroll
    for (int j = 0; j < 5; ++j) {
      const int cc = c4 + 8 * j;                 // 0..39
      const int n  = cc >> 2, o4 = (cc & 3) << 2;
      pw[s][j] = *(const float4*)(W + (size_t)n * WSTRIDE +
                                  (size_t)(k0 + s * 32 + kl) * COUT + o4);
    }

  // ---- x: direct global -> A-fragment (no LDS round-trip) ----
  const float* xrow = x + (size_t)(b0 + wv * 16 + m16) * KDIM + k0 + q * 8;
  float4 pa[STEPS][2];
#pragma unroll
  for (int s = 0; s < STEPS; ++s) {
    pa[s][0] = *(const float4*)(xrow + s * 32);
    pa[s][1] = *(const float4*)(xrow + s * 32 + 4);
  }

  f32x4 acc[NCAPS];
#pragma unroll
  for (int i = 0; i < NCAPS; ++i) acc[i] = (f32x4){0.f, 0.f, 0.f, 0.f};

#pragma unroll
  for (int s = 0; s < STEPS; ++s) {
    // stage W step s (transpose to [col][k] bf16)
#pragma unroll
    for (int j = 0; j < 5; ++j) {
      const int cc = c4 + 8 * j;
      const int n  = cc >> 2, o4 = (cc & 3) << 2;
      const int cb = (n * COUT + o4) * LROW + kl;
      unsigned short* b = &wbuf[s][0];
      b[cb + 0 * LROW] = f2bf(pw[s][j].x);
      b[cb + 1 * LROW] = f2bf(pw[s][j].y);
      b[cb + 2 * LROW] = f2bf(pw[s][j].z);
      b[cb + 3 * LROW] = f2bf(pw[s][j].w);
    }
    __syncthreads();   // distinct buffers per step -> only write->read barrier needed

    bf16x8 a;
    a[0] = (short)f2bf(pa[s][0].x); a[1] = (short)f2bf(pa[s][0].y);
    a[2] = (short)f2bf(pa[s][0].z); a[3] = (short)f2bf(pa[s][0].w);
    a[4] = (short)f2bf(pa[s][1].x); a[5] = (short)f2bf(pa[s][1].y);
    a[6] = (short)f2bf(pa[s][1].z); a[7] = (short)f2bf(pa[s][1].w);
#pragma unroll
    for (int nt = 0; nt < NCAPS; ++nt) {
      bf16x8 bf = *(const bf16x8*)&wbuf[s][(nt * COUT + m16) * LROW + q * 8];
      acc[nt] = __builtin_amdgcn_mfma_f32_16x16x32_bf16(a, bf, acc[nt], 0, 0, 0);
    }
  }

  // ---- deterministic partial store: P[bid][n][row64][o] ----
  float* P = ws + (size_t)bid * PARTL;
  const int br = wv * 16 + q * 4;   // + r
#pragma unroll
  for (int nt = 0; nt < NCAPS; ++nt)
#pragma unroll
    for (int r = 0; r < 4; ++r)
      P[nt * 1024 + (br + r) * COUT + m16] = acc[nt][r];

  // ---- publish: device-scope release of this block's flag ----
  unsigned int* flags = (unsigned int*)(ws + FLAGS_OFF);
  __threadfence();
  __syncthreads();
  if (tid == 0)
    __hip_atomic_store(&flags[bid], MAGIC, __ATOMIC_RELEASE, __HIP_MEMORY_SCOPE_AGENT);

  if (bid >= 160) return;   // pure producers exit, freeing CUs

  // ---- reducer role: block bid handles outputs L = seg*256 + tid of M-tile mt ----
  // (mt = bid&3, seg = bid>>2 — same mapping as the old caps_reduce grid)
  const int seg = bid >> 2;
  const int L   = seg * 256 + tid;          // [0,10240)

  // wait for all 96 producers of this mt (tid<96 each spins on one flag)
  if (tid < SPLITS) {
    const unsigned int* f = &flags[tid * 4 + mt];
    while (__hip_atomic_load(f, __ATOMIC_ACQUIRE, __HIP_MEMORY_SCOPE_AGENT) != MAGIC)
      __builtin_amdgcn_s_sleep(8);
  }
  __syncthreads();

  const float* p = ws + (size_t)mt * PARTL + L;
  float s0 = 0.f, s1 = 0.f, s2 = 0.f, s3 = 0.f;
#pragma unroll 4
  for (int kk = 0; kk < SPLITS; kk += 4) {
    s0 += p[(size_t)(kk + 0) * (4 * PARTL)];
    s1 += p[(size_t)(kk + 1) * (4 * PARTL)];
    s2 += p[(size_t)(kk + 2) * (4 * PARTL)];
    s3 += p[(size_t)(kk + 3) * (4 * PARTL)];
  }
  float s = ((s0 + s1) + (s2 + s3)) * (1.0f / (float)RNODES);

  float sq = s * s;
  sq += __shfl_xor(sq, 1);
  sq += __shfl_xor(sq, 2);
  sq += __shfl_xor(sq, 4);
  sq += __shfl_xor(sq, 8);
  const int n = L >> 10, rem = L & 1023;
  out[n * 4096 + mt * 1024 + rem] = s * sqrtf(sq) / (1.0f + sq);
}

extern "C" void kernel_launch(void* const* d_in, const int* in_sizes, int n_in,
                              void* d_out, int out_size, void* d_ws, size_t ws_size,
                              hipStream_t stream) {
  const float* x = (const float*)d_in[0];   // [256,1152,8] fp32
  const float* W = (const float*)d_in[1];   // [10,1152,8,16] fp32
  float* ws  = (float*)d_ws;                // partials (15.7 MB) + flags
  float* out = (float*)d_out;               // 40960 fp32

  caps_fused<<<dim3(NBLK), dim3(256), 0, stream>>>(x, W, ws, out);
}

// Round 4
// 73.022 us; speedup vs baseline: 1.8978x; 1.8978x over previous
//
#include <hip/hip_runtime.h>

#define RNODES 1152
#define KDIM 9216                 // 1152*8
#define COUT 16
#define NCAPS 10
#define WSTRIDE (KDIM*COUT)       // 147456 floats per capsule

#define LROW 40                   // 32 k + 8 pad (ushorts) -> 80B rows
#define WBUF (NCAPS*COUT*LROW)    // 6400 ushorts = 12.8 KB per buffer
#define STEPS 6                   // k-steps of 32 per block
#define SPLITS 48                 // 48 * 6 * 32 = 9216 = KDIM
#define NBLK (SPLITS*4)           // 192 blocks
#define PARTL 10240               // per-block partial: 10 caps * 64 rows * 16

using bf16x8 = __attribute__((ext_vector_type(8))) short;
using f32x4  = __attribute__((ext_vector_type(4))) float;

__device__ __forceinline__ unsigned short f2bf(float f) {
  unsigned int u = __builtin_bit_cast(unsigned int, f);
  u += 0x7FFFu + ((u >> 16) & 1u);   // round-to-nearest-even
  return (unsigned short)(u >> 16);
}

// grid = 192: bid -> (ks = bid>>2, mt = bid&3). All 42 float4 loads issued
// up front (launch_bounds(256,1) -> ~230 VGPRs so they truly stay in flight:
// R3's counter showed VGPR_Count=64 had serialized the prefetch). Issue order
// interleaved by step so step-0 consumption leaves later loads outstanding.
__global__ __launch_bounds__(256, 1) void caps_gemm(const float* __restrict__ x,
                                                    const float* __restrict__ W,
                                                    float* __restrict__ ws) {
  __shared__ unsigned short wbuf[2][WBUF];   // ping-pong, 25.6 KB
  const int tid = threadIdx.x;
  const int bid = blockIdx.x;
  const int ks  = bid >> 2;
  const int mt  = bid & 3;
  const int b0  = mt * 64;
  const int k0  = ks * (STEPS * 32);

  const int lane = tid & 63;
  const int wv   = tid >> 6;        // wave -> 16-row sub-tile
  const int q    = lane >> 4;       // k-quad
  const int m16  = lane & 15;

  const int c4 = tid >> 5;          // W decode: + 8*j
  const int kl = tid & 31;
  const float* xrow = x + (size_t)(b0 + wv * 16 + m16) * KDIM + k0 + q * 8;

  float4 pw[STEPS][5];
  float4 pa[STEPS][2];
#pragma unroll
  for (int s = 0; s < STEPS; ++s) {
#pragma unroll
    for (int j = 0; j < 5; ++j) {
      const int cc = c4 + 8 * j;                 // 0..39
      const int n  = cc >> 2, o4 = (cc & 3) << 2;
      pw[s][j] = *(const float4*)(W + (size_t)n * WSTRIDE +
                                  (size_t)(k0 + s * 32 + kl) * COUT + o4);
    }
    pa[s][0] = *(const float4*)(xrow + s * 32);
    pa[s][1] = *(const float4*)(xrow + s * 32 + 4);
  }

  f32x4 acc[NCAPS];
#pragma unroll
  for (int i = 0; i < NCAPS; ++i) acc[i] = (f32x4){0.f, 0.f, 0.f, 0.f};

#pragma unroll
  for (int s = 0; s < STEPS; ++s) {
    // stage W step s (transpose to [col][k] bf16) into ping-pong buffer.
    // Safety: write(s+1) vs read(s-1) on the same buffer are separated by
    // barrier(s) — classic double-buffer, one barrier per step.
    unsigned short* b = &wbuf[s & 1][0];
#pragma unroll
    for (int j = 0; j < 5; ++j) {
      const int cc = c4 + 8 * j;
      const int n  = cc >> 2, o4 = (cc & 3) << 2;
      const int cb = (n * COUT + o4) * LROW + kl;
      b[cb + 0 * LROW] = f2bf(pw[s][j].x);
      b[cb + 1 * LROW] = f2bf(pw[s][j].y);
      b[cb + 2 * LROW] = f2bf(pw[s][j].z);
      b[cb + 3 * LROW] = f2bf(pw[s][j].w);
    }
    __syncthreads();

    bf16x8 a;
    a[0] = (short)f2bf(pa[s][0].x); a[1] = (short)f2bf(pa[s][0].y);
    a[2] = (short)f2bf(pa[s][0].z); a[3] = (short)f2bf(pa[s][0].w);
    a[4] = (short)f2bf(pa[s][1].x); a[5] = (short)f2bf(pa[s][1].y);
    a[6] = (short)f2bf(pa[s][1].z); a[7] = (short)f2bf(pa[s][1].w);
#pragma unroll
    for (int nt = 0; nt < NCAPS; ++nt) {
      bf16x8 bf = *(const bf16x8*)&b[(nt * COUT + m16) * LROW + q * 8];
      acc[nt] = __builtin_amdgcn_mfma_f32_16x16x32_bf16(a, bf, acc[nt], 0, 0, 0);
    }
  }

  // ---- deterministic partial store: P[bid][n][row64][o] ----
  float* P = ws + (size_t)bid * PARTL;
  const int br = wv * 16 + q * 4;   // + r  (C/D: col=lane&15, row=q*4+reg)
#pragma unroll
  for (int nt = 0; nt < NCAPS; ++nt)
#pragma unroll
    for (int r = 0; r < 4; ++r)
      P[nt * 1024 + (br + r) * COUT + m16] = acc[nt][r];
}

// grid = 160 x 256: block handles 256 outputs of M-tile mt, sums 48 splits
// (all 48 loads issued before the adds), then squashes over 16-lane o-groups.
__global__ __launch_bounds__(256, 1) void caps_reduce(const float* __restrict__ ws,
                                                      float* __restrict__ out) {
  const int tid = threadIdx.x;
  const int mt  = blockIdx.x & 3;
  const int seg = blockIdx.x >> 2;
  const int L   = seg * 256 + tid;          // [0,10240)

  const float* p = ws + (size_t)mt * PARTL + L;
  float s0 = 0.f, s1 = 0.f, s2 = 0.f, s3 = 0.f;
#pragma unroll
  for (int kk = 0; kk < SPLITS; kk += 4) {
    s0 += p[(size_t)(kk + 0) * (4 * PARTL)];
    s1 += p[(size_t)(kk + 1) * (4 * PARTL)];
    s2 += p[(size_t)(kk + 2) * (4 * PARTL)];
    s3 += p[(size_t)(kk + 3) * (4 * PARTL)];
  }
  float s = ((s0 + s1) + (s2 + s3)) * (1.0f / (float)RNODES);

  float sq = s * s;
  sq += __shfl_xor(sq, 1);
  sq += __shfl_xor(sq, 2);
  sq += __shfl_xor(sq, 4);
  sq += __shfl_xor(sq, 8);
  const int n = L >> 10, rem = L & 1023;
  out[n * 4096 + mt * 1024 + rem] = s * sqrtf(sq) / (1.0f + sq);
}

extern "C" void kernel_launch(void* const* d_in, const int* in_sizes, int n_in,
                              void* d_out, int out_size, void* d_ws, size_t ws_size,
                              hipStream_t stream) {
  const float* x = (const float*)d_in[0];   // [256,1152,8] fp32
  const float* W = (const float*)d_in[1];   // [10,1152,8,16] fp32
  float* ws  = (float*)d_ws;                // 192*10240 fp32 partials (7.9 MB)
  float* out = (float*)d_out;               // 40960 fp32

  caps_gemm<<<dim3(NBLK), dim3(256), 0, stream>>>(x, W, ws);
  caps_reduce<<<dim3(160), dim3(256), 0, stream>>>(ws, out);
}